// Round 10
// baseline (8299.730 us; speedup 1.0000x reference)
//
#include <hip/hip_runtime.h>
#include <hip/hip_bf16.h>
#include <math.h>

// Problem constants (fixed by setup_inputs): B=64, L=512, D_IN=256, H=256, A=128, DEPTH=4
#define BB 64
#define LL 512
#define HH 256
#define H3 768
#define AA 128
#define NDEPTH 4
#define NROWS (LL*BB)   // 32768

// u64 exch[64 chains][2 parity][3 slices][256] = 786,432 B (dedicated ws)
#define EXCH_U64_PER_CHAIN (2 * 3 * 256)

typedef float vf32x32 __attribute__((ext_vector_type(32)));

// ---------------------------------------------------------------------------
// Mask conversion: detect byte-bool vs int32/float32 layout on device.
// mask[0][1] is always true (lengths >= 256 > 1): byte layout -> raw[1]==1.
__global__ void maskcvt_kernel(const unsigned char* __restrict__ raw,
                               int* __restrict__ m)
{
    int i = blockIdx.x * blockDim.x + threadIdx.x;   // 32768 threads
    bool bytemode = (raw[1] == 1);
    int v;
    if (bytemode) v = raw[i] ? 1 : 0;
    else          v = (((const int*)raw)[i] != 0) ? 1 : 0;
    m[i] = v;
}

// ---------------------------------------------------------------------------
// Per-chain compaction index: rowidx[b*512+seq] = seq-th active l (ascending),
// nact[b] = count. Ballot prefix sum, one 512-thread block per chain.
__global__ __launch_bounds__(512) void mkidx_kernel(
    const int* __restrict__ m,      // [b*512+l]
    int* __restrict__ rowidx,       // [b*512+seq] -> l
    int* __restrict__ nact)         // [b]
{
    const int b    = blockIdx.x;
    const int tid  = threadIdx.x;   // = l
    const int lane = tid & 63;
    const int w    = tid >> 6;      // 8 waves
    __shared__ int wcnt[8];
    int pred = m[b * LL + tid];
    unsigned long long bal = __ballot(pred != 0);
    int below = __popcll(bal & ((1ull << lane) - 1ull));
    if (lane == 63) wcnt[w] = __popcll(bal);
    __syncthreads();
    int woff = 0;
#pragma unroll
    for (int i = 0; i < 8; ++i) woff += (i < w) ? wcnt[i] : 0;
    if (pred) rowidx[b * LL + woff + below] = tid;
    if (tid == 511) nact[b] = woff + wcnt[7];
}

// ---------------------------------------------------------------------------
// Tiled fp32 GEMM: C[M,N] = A[M,256] @ B[256,N]  (K fixed at 256)
// MODE 1: A[row,k] = A[(row&63)*131072 + (row>>6)*256 + k]   (x gather)
// MODE 3: compacted-chain gather: out row r=(b*512+seq) pulls A row
//         (rowidx[r]*64+b); whole 128-row tiles past nact[b] exit early.
// EPI 0: store acc; EPI 1: + bias[col]
template<int MODE, int EPI>
__global__ __launch_bounds__(256) void gemm_kernel(
    const float* __restrict__ A, const float* __restrict__ Bm,
    const float* __restrict__ bias,
    float* __restrict__ C, int M, int N,
    const int* __restrict__ ridx, const int* __restrict__ nact)
{
    __shared__ float As[16][136];
    __shared__ float Bs[16][136];
    const int tid = threadIdx.x;
    const int tx = tid & 15, ty = tid >> 4;
    const int row0 = blockIdx.y * 128, col0 = blockIdx.x * 128;

    int arow0 = 0, arow1 = 0;
    if (MODE == 3) {
        const int bb = row0 >> 9;               // chain of this tile
        const int na = nact[bb];
        if ((row0 & 511) >= na) return;         // fully-inactive tile: skip
        const int r0 = row0 + (tid >> 2);       // i=0 staging row
        const int r1 = r0 + 64;                 // i=1 staging row
        const int l0 = ((r0 & 511) < na) ? ridx[r0] : 0;
        const int l1 = ((r1 & 511) < na) ? ridx[r1] : 0;
        arow0 = l0 * 64 + bb;
        arow1 = l1 * 64 + bb;
    }

    float acc[8][8];
#pragma unroll
    for (int i = 0; i < 8; ++i)
#pragma unroll
        for (int j = 0; j < 8; ++j) acc[i][j] = 0.f;

    for (int kk = 0; kk < 256; kk += 16) {
#pragma unroll
        for (int i = 0; i < 2; ++i) {
            int aid = i * 256 + tid;
            int r   = aid >> 2;
            int k4  = (aid & 3) << 2;
            int rr  = row0 + r;
            float4 v;
            if (MODE == 1) {
                v = *(const float4*)(A + (rr & 63) * 131072 + (rr >> 6) * 256 + kk + k4);
            } else {
                int ar = i ? arow1 : arow0;
                v = *(const float4*)(A + ar * 256 + kk + k4);
            }
            As[k4 + 0][r] = v.x; As[k4 + 1][r] = v.y;
            As[k4 + 2][r] = v.z; As[k4 + 3][r] = v.w;

            int bid = i * 256 + tid;
            int bk  = bid >> 5;
            int c4  = (bid & 31) << 2;
            float4 w = *(const float4*)(Bm + (kk + bk) * N + col0 + c4);
            *(float4*)&Bs[bk][c4] = w;
        }
        __syncthreads();
#pragma unroll
        for (int k = 0; k < 16; ++k) {
            float a[8], bb2[8];
            *(float4*)&a[0]   = *(const float4*)&As[k][ty * 8];
            *(float4*)&a[4]   = *(const float4*)&As[k][ty * 8 + 4];
            *(float4*)&bb2[0] = *(const float4*)&Bs[k][tx * 8];
            *(float4*)&bb2[4] = *(const float4*)&Bs[k][tx * 8 + 4];
#pragma unroll
            for (int i = 0; i < 8; ++i)
#pragma unroll
                for (int j = 0; j < 8; ++j)
                    acc[i][j] += a[i] * bb2[j];
        }
        __syncthreads();
    }

#pragma unroll
    for (int i = 0; i < 8; ++i) {
        int row  = row0 + ty * 8 + i;
        int colb = col0 + tx * 8;
        float vout[8];
#pragma unroll
        for (int j = 0; j < 8; ++j) {
            float v = acc[i][j];
            if (EPI == 1) v += bias[colb + j];
            vout[j] = v;
        }
        *(float4*)&C[row * N + colb]     = *(float4*)&vout[0];
        *(float4*)&C[row * N + colb + 4] = *(float4*)&vout[4];
    }
}

// ---------------------------------------------------------------------------
// Row LayerNorm over 768 cols, in place, fused with gamma/beta and gate bias.
// Compacted-row variant: rows past nact[chain] are garbage -> skipped.
__global__ __launch_bounds__(256) void lnrows_kernel(
    float* __restrict__ XP, const float* __restrict__ g0,
    const float* __restrict__ b0, const float* __restrict__ gb,
    const int* __restrict__ nact)
{
    const int row = blockIdx.x;
    if ((row & 511) >= nact[row >> 9]) return;
    const int tid = threadIdx.x;
    float* p = XP + (long)row * H3;
    float v0 = p[tid], v1 = p[tid + 256], v2 = p[tid + 512];
    float s = v0 + v1 + v2;
    float q = v0 * v0 + v1 * v1 + v2 * v2;
#pragma unroll
    for (int off = 32; off >= 1; off >>= 1) {
        s += __shfl_xor(s, off);
        q += __shfl_xor(q, off);
    }
    __shared__ float rs4[4], rq4[4];
    if ((tid & 63) == 0) { rs4[tid >> 6] = s; rq4[tid >> 6] = q; }
    __syncthreads();
    float S = rs4[0] + rs4[1] + rs4[2] + rs4[3];
    float Q = rq4[0] + rq4[1] + rq4[2] + rq4[3];
    float mu  = S * (1.f / 768.f);
    float var = Q * (1.f / 768.f) - mu * mu;
    float r   = rsqrtf(var + 1e-5f);
    p[tid]       = g0[tid]       * (v0 - mu) * r + b0[tid]       + gb[tid];
    p[tid + 256] = g0[tid + 256] * (v1 - mu) * r + b0[tid + 256] + gb[tid + 256];
    p[tid + 512] = g0[tid + 512] * (v2 - mu) * r + b0[tid + 512] + gb[tid + 512];
}

// ---------------------------------------------------------------------------
// Combined dispatch (448 blocks, 512 threads):
//   blocks [0,192): the sequential GRU scan (round-9 structure, best measured)
//   blocks [192,448): ACTION tiles — tile t (rows 128t..128t+127, l=2t,2t+1)
//     computes v = tanh(Yprev@Ua1 + X@Wa1 + ba1), logits = v@Wa2+ba2, softmax,
//     decision, next-depth mask. Gated on cnt[2t] == 64*(d+1): slice-0 scan
//     wgs release-add cnt[l] after their Y-row stores drain, so act tiles
//     stream BEHIND the scan and their cost hides under the scan's latency-
//     bound critical path (round-9: XA rode free the same way).
// Coherence: Y written with AGENT-scope atomic stores (LLC write-through);
// act tiles read Yprev with AGENT-scope relaxed atomic loads (bypass the
// non-coherent per-XCD L2 — Y's buffer was cached by earlier depths).
// Deadlock safety: scan blocks are the first 192 IDs (placed first, same
// co-residency assumption as rounds 2-9); act blocks retire.
// LDS manually unioned (35 KB) so scan keeps 2 wgs/CU.
__global__ __launch_bounds__(512, 2) void scanact_kernel(
    const float* __restrict__ XP,   // compacted (b*512+cs, 768), bias+LN folded
    const float* __restrict__ U,    // (256, 768)
    const float* __restrict__ g1, const float* __restrict__ b1,
    const int* __restrict__ mask,   // [b*512+l] (current depth, = act mask_in)
    float* __restrict__ Y,          // (L*B, 256)
    unsigned long long* __restrict__ exch,  // [64][2][3][256] u64 (dedicated)
    int seq0,                       // d<<10
    const float* __restrict__ Xc,   // (L*B, 256) current depth input
    const float* __restrict__ Wa1, const float* __restrict__ ba1,
    const float* __restrict__ Ua1,
    const float* __restrict__ Wa2, const float* __restrict__ ba2,
    int* __restrict__ mask_out,
    float* __restrict__ act_out, float* __restrict__ pol_out,
    int d,
    int* __restrict__ cnt)          // [512] progress counters (accumulate 64/depth)
{
    __shared__ __align__(16) char smem[34816];
    const int tid = threadIdx.x;

    if (blockIdx.x >= 192) {
        // ================= action-tile path =================
        float (*As1)[136] = (float(*)[136])(smem);            // Yprev tile
        float (*As2)[136] = (float(*)[136])(smem + 8704);     // X tile
        float (*Bs1)[136] = (float(*)[136])(smem + 17408);    // Ua1
        float (*Bs2)[136] = (float(*)[136])(smem + 26112);    // Wa1
        const int t    = blockIdx.x - 192;   // 0..255
        const int row0 = t * 128;

        // wait until every chain has written Y row l = 2t (rows <= 2t done)
        if (tid == 0) {
            const int target = 64 * (d + 1);
            int spins = 0;
            while (__hip_atomic_load(&cnt[2 * t], __ATOMIC_ACQUIRE,
                                     __HIP_MEMORY_SCOPE_AGENT) < target) {
                if (++spins > 8) __builtin_amdgcn_s_sleep(8);
            }
        }
        __syncthreads();

        const int tx = tid & 15;   // 8 cols each
        const int ty = tid >> 4;   // 0..31 -> 4 rows each
        float acc[4][8];
#pragma unroll
        for (int i = 0; i < 4; ++i)
#pragma unroll
            for (int j = 0; j < 8; ++j) acc[i][j] = 0.f;

        for (int kk = 0; kk < 256; kk += 16) {
            {   // A stages: 128x16 each, one pass (512 thr x 4 floats)
                int r  = tid >> 2;
                int k4 = (tid & 3) << 2;
                int rr = row0 + r;
                float4 v1;
                if (rr < 64) v1 = make_float4(0.f, 0.f, 0.f, 0.f);
                else {
                    const float* yp = Y + (rr - 64) * 256 + kk + k4;
                    v1.x = __hip_atomic_load(yp + 0, __ATOMIC_RELAXED, __HIP_MEMORY_SCOPE_AGENT);
                    v1.y = __hip_atomic_load(yp + 1, __ATOMIC_RELAXED, __HIP_MEMORY_SCOPE_AGENT);
                    v1.z = __hip_atomic_load(yp + 2, __ATOMIC_RELAXED, __HIP_MEMORY_SCOPE_AGENT);
                    v1.w = __hip_atomic_load(yp + 3, __ATOMIC_RELAXED, __HIP_MEMORY_SCOPE_AGENT);
                }
                As1[k4 + 0][r] = v1.x; As1[k4 + 1][r] = v1.y;
                As1[k4 + 2][r] = v1.z; As1[k4 + 3][r] = v1.w;
                float4 v2 = *(const float4*)(Xc + rr * 256 + kk + k4);
                As2[k4 + 0][r] = v2.x; As2[k4 + 1][r] = v2.y;
                As2[k4 + 2][r] = v2.z; As2[k4 + 3][r] = v2.w;
            }
            {   // B stages: 16x128 each, one pass
                int bk = tid >> 5;
                int c4 = (tid & 31) << 2;
                *(float4*)&Bs1[bk][c4] = *(const float4*)(Ua1 + (kk + bk) * AA + c4);
                *(float4*)&Bs2[bk][c4] = *(const float4*)(Wa1 + (kk + bk) * AA + c4);
            }
            __syncthreads();
#pragma unroll
            for (int k = 0; k < 16; ++k) {
                float a1[4], a2[4], w1[8], w2[8];
                *(float4*)&a1[0] = *(const float4*)&As1[k][ty * 4];
                *(float4*)&a2[0] = *(const float4*)&As2[k][ty * 4];
                *(float4*)&w1[0] = *(const float4*)&Bs1[k][tx * 8];
                *(float4*)&w1[4] = *(const float4*)&Bs1[k][tx * 8 + 4];
                *(float4*)&w2[0] = *(const float4*)&Bs2[k][tx * 8];
                *(float4*)&w2[4] = *(const float4*)&Bs2[k][tx * 8 + 4];
#pragma unroll
                for (int i = 0; i < 4; ++i)
#pragma unroll
                    for (int j = 0; j < 8; ++j)
                        acc[i][j] += a1[i] * w1[j] + a2[i] * w2[j];
            }
            __syncthreads();
        }

        // epilogue: tanh + logit partials over this thread's 8 cols
        float p0[4], p1[4];
#pragma unroll
        for (int i = 0; i < 4; ++i) { p0[i] = 0.f; p1[i] = 0.f; }
#pragma unroll
        for (int i = 0; i < 4; ++i)
#pragma unroll
            for (int j = 0; j < 8; ++j) {
                int c   = tx * 8 + j;
                float v = tanhf(acc[i][j] + ba1[c]);
                p0[i] += v * Wa2[c * 2];
                p1[i] += v * Wa2[c * 2 + 1];
            }
#pragma unroll
        for (int off = 1; off < 16; off <<= 1)
#pragma unroll
            for (int i = 0; i < 4; ++i) {
                p0[i] += __shfl_xor(p0[i], off);
                p1[i] += __shfl_xor(p1[i], off);
            }
        if (tx == 0) {
#pragma unroll
            for (int i = 0; i < 4; ++i) {
                int row = row0 + ty * 4 + i;
                int l   = row >> 6, bb = row & 63;
                float l0 = p0[i] + ba2[0];
                float l1 = p1[i] + ba2[1];
                float m  = fmaxf(l0, l1);
                float e0 = expf(l0 - m), e1 = expf(l1 - m);
                float inv = 1.f / (e0 + e1);
                float q0 = e0 * inv, q1v = e1 * inv;
                int mt = mask[bb * LL + l];
                int a  = (q1v > q0) && mt;
                act_out[bb * (NDEPTH * LL) + d * LL + l] = a ? 1.f : 0.f;
                pol_out[bb * (NDEPTH * LL * 2) + d * (LL * 2) + l * 2 + 0] = q0;
                pol_out[bb * (NDEPTH * LL * 2) + d * (LL * 2) + l * 2 + 1] = q1v;
                mask_out[bb * LL + l] = a;
            }
        }
        return;
    }

    // ================= scan path =================
    float* h_cur        = (float*)smem;                    // 256
    float (*part)[256]  = (float(*)[256])(smem + 1024);    // [16][256]
    float* xp_lds       = (float*)(smem + 17408);          // 768
    float* g1s          = (float*)(smem + 20480);          // 768
    float* b1s          = (float*)(smem + 23552);          // 768
    int*   mk           = (int*)(smem + 26624);            // 512
    float* reds         = (float*)(smem + 28672);          // 4
    float* redq         = (float*)(smem + 28688);          // 4

    const int i0   = blockIdx.x;
    const int xcd  = i0 & 7;
    const int slot = i0 >> 3;              // 0..23
    const int b    = xcd + 8 * (slot / 3); // chain 0..63
    const int s    = slot % 3;             // slice 0..2
    const int kg   = tid >> 5;             // 16 k-groups (16 k each)
    const int cg   = tid & 31;             // col ownership: cg + 32*j
    const int q1   = (s + 1 >= 3) ? s - 2 : s + 1;
    const int q2   = (s + 2 >= 3) ? s - 1 : s + 2;

    // U slice -> registers via volatile loads (pinned against remat/sinking).
    vf32x32 u0v, u1v, u2v, u3v;
    {
        const volatile float* Uv = U;
        const int colbase = s * 256 + cg;
#pragma unroll
        for (int i = 0; i < 16; ++i) {
#pragma unroll
            for (int j = 0; j < 8; ++j) {
                const int f = i * 8 + j;
                float val = Uv[(kg * 16 + i) * H3 + colbase + 32 * j];
                if      (f < 32) u0v[f]      = val;
                else if (f < 64) u1v[f - 32] = val;
                else if (f < 96) u2v[f - 64] = val;
                else             u3v[f - 96] = val;
            }
        }
    }
    if (tid < 256) h_cur[tid] = 0.f;
    for (int i = tid; i < 768; i += 512) { g1s[i] = g1[i]; b1s[i] = b1[i]; }
    mk[tid] = mask[b * LL + tid];
    __syncthreads();

    unsigned long long* exb = exch + b * EXCH_U64_PER_CHAIN;
    int seq = seq0;

    for (int l = 0; l < LL; ++l) {
        if (!mk[l]) {
            // masked step: h unchanged; slice 0 writes Y row (agent atomics,
            // wave 0 only) then release-adds cnt[l] (drains wave-0 stores).
            if (s == 0) {
                if (tid < 64) {
                    float* yp = Y + ((long)l * BB + b) * HH + tid * 4;
                    const float* hc = h_cur + tid * 4;
                    __hip_atomic_store(yp + 0, hc[0], __ATOMIC_RELAXED, __HIP_MEMORY_SCOPE_AGENT);
                    __hip_atomic_store(yp + 1, hc[1], __ATOMIC_RELAXED, __HIP_MEMORY_SCOPE_AGENT);
                    __hip_atomic_store(yp + 2, hc[2], __ATOMIC_RELAXED, __HIP_MEMORY_SCOPE_AGENT);
                    __hip_atomic_store(yp + 3, hc[3], __ATOMIC_RELAXED, __HIP_MEMORY_SCOPE_AGENT);
                }
                if (tid == 0)
                    __hip_atomic_fetch_add(&cnt[l], 1, __ATOMIC_RELEASE, __HIP_MEMORY_SCOPE_AGENT);
            }
            continue;
        }
        seq++;
        const int par = seq & 1;
        const int cs  = seq - seq0 - 1;        // compacted XP row index

        // prefetch compacted xp row (in flight during GEMV)
        float4 xr4;
        if (tid < 192) xr4 = *(const float4*)(XP + ((long)(b * LL + cs)) * H3 + tid * 4);

        // slice GEMV: acc[j] = sum_{k in kg-chunk} U[k][colbase+32j] * h[k]
        float acc[8] = {0.f, 0.f, 0.f, 0.f, 0.f, 0.f, 0.f, 0.f};
#pragma unroll
        for (int i = 0; i < 4; ++i) {
            float4 hv = *(const float4*)&h_cur[kg * 16 + i * 4];   // broadcast
#pragma unroll
            for (int e = 0; e < 4; ++e) {
                const float hh = (e == 0) ? hv.x : (e == 1) ? hv.y
                               : (e == 2) ? hv.z : hv.w;
                const int ik = i * 4 + e;
#pragma unroll
                for (int j = 0; j < 8; ++j) {
                    const int f = ik * 8 + j;
                    const float uu = (f < 32) ? u0v[f]
                                   : (f < 64) ? u1v[f - 32]
                                   : (f < 96) ? u2v[f - 64]
                                   :            u3v[f - 96];
                    acc[j] += uu * hh;
                }
            }
        }
#pragma unroll
        for (int j = 0; j < 8; ++j)
            part[kg][cg + 32 * j] = acc[j];            // bank=cg: conflict-free
        __syncthreads();                               // B1: part complete

        if (tid < 192) *(float4*)&xp_lds[tid * 4] = xr4;

        float pre = 0.f, v0 = 0.f, v1 = 0.f, v2 = 0.f;
        if (tid < 256) {
            pre = part[0][tid];
#pragma unroll
            for (int gg = 1; gg < 16; ++gg) pre += part[gg][tid];

            // publish own slice value (data+seq packed, relaxed agent atomic)
            unsigned long long pk =
                ((unsigned long long)(unsigned)seq << 32) |
                (unsigned long long)__float_as_uint(pre);
            __hip_atomic_store(&exb[(par * 3 + s) * 256 + tid], pk,
                               __ATOMIC_RELAXED, __HIP_MEMORY_SCOPE_AGENT);

            // fused dual-poll with bounded-sleep backoff
            unsigned long long x1 = 0, x2 = 0;
            bool d1 = false, d2 = false;
            int spins = 0;
            do {
                unsigned long long t1 =
                    __hip_atomic_load(&exb[(par * 3 + q1) * 256 + tid],
                                      __ATOMIC_RELAXED, __HIP_MEMORY_SCOPE_AGENT);
                unsigned long long t2 =
                    __hip_atomic_load(&exb[(par * 3 + q2) * 256 + tid],
                                      __ATOMIC_RELAXED, __HIP_MEMORY_SCOPE_AGENT);
                if (!d1 && (int)(t1 >> 32) == seq) { x1 = t1; d1 = true; }
                if (!d2 && (int)(t2 >> 32) == seq) { x2 = t2; d2 = true; }
                if (++spins > 8) __builtin_amdgcn_s_sleep(1);
            } while (!(d1 && d2));
            float w1 = __uint_as_float((unsigned)x1);
            float w2 = __uint_as_float((unsigned)x2);
            v0 = (s == 0) ? pre : ((q1 == 0) ? w1 : w2);
            v1 = (s == 1) ? pre : ((q1 == 1) ? w1 : w2);
            v2 = (s == 2) ? pre : ((q1 == 2) ? w1 : w2);

            float st = v0 + v1 + v2;
            float qt = v0 * v0 + v1 * v1 + v2 * v2;
#pragma unroll
            for (int off = 32; off >= 1; off >>= 1) {
                st += __shfl_xor(st, off);
                qt += __shfl_xor(qt, off);
            }
            if ((tid & 63) == 0) { reds[tid >> 6] = st; redq[tid >> 6] = qt; }
        }
        __syncthreads();                               // B2: stats partials

        if (tid < 256) {
            float S = reds[0] + reds[1] + reds[2] + reds[3];
            float Q = redq[0] + redq[1] + redq[2] + redq[3];
            float mu = S * (1.f / 768.f);
            float rs = rsqrtf(Q * (1.f / 768.f) - mu * mu + 1e-5f);
            float hp_r = g1s[tid]       * (v0 - mu) * rs + b1s[tid];
            float hp_z = g1s[256 + tid] * (v1 - mu) * rs + b1s[256 + tid];
            float hp_h = g1s[512 + tid] * (v2 - mu) * rs + b1s[512 + tid];
            float xr = xp_lds[tid], xz = xp_lds[256 + tid], xh = xp_lds[512 + tid];
            float r  = 1.f / (1.f + expf(-(xr + hp_r)));
            float z  = 1.f / (1.f + expf(-(xz + hp_z)));
            float hh = tanhf(xh + r * hp_h);
            float o  = z * h_cur[tid] + (1.f - z) * hh;   // active step: mt=1
            h_cur[tid] = o;
            if (s == 0)
                __hip_atomic_store(&Y[((long)l * BB + b) * HH + tid], o,
                                   __ATOMIC_RELAXED, __HIP_MEMORY_SCOPE_AGENT);
        }
        __syncthreads();                               // B3: h ready; all waves'
        if (s == 0 && tid == 0)                        // Y stores drained (pre-
            __hip_atomic_fetch_add(&cnt[l], 1,         // barrier vmcnt(0))
                                   __ATOMIC_RELEASE, __HIP_MEMORY_SCOPE_AGENT);
    }
}

// ---------------------------------------------------------------------------
__global__ void final_copy_kernel(const float* __restrict__ X, float* __restrict__ out)
{
    int i = blockIdx.x * blockDim.x + threadIdx.x;   // 16384
    int bb = i >> 8, j = i & 255;
    out[i] = X[((long)(LL - 1) * BB + bb) * HH + j];
}

// ---------------------------------------------------------------------------
extern "C" void kernel_launch(void* const* d_in, const int* in_sizes, int n_in,
                              void* d_out, int out_size, void* d_ws, size_t ws_size,
                              hipStream_t stream)
{
    const float* x      = (const float*)d_in[0];
    const void*  mraw   = d_in[1];
    const float* W_emb  = (const float*)d_in[2];
    const float* b_emb  = (const float*)d_in[3];
    const float* W      = (const float*)d_in[4];
    const float* U      = (const float*)d_in[5];
    const float* bias3  = (const float*)d_in[6];
    const float* Wa1    = (const float*)d_in[7];
    const float* Ua1    = (const float*)d_in[8];
    const float* ba1    = (const float*)d_in[9];
    const float* Wa2    = (const float*)d_in[10];
    const float* ba2    = (const float*)d_in[11];
    const float* gammas = (const float*)d_in[12];
    const float* betas  = (const float*)d_in[13];

    float* out = (float*)d_out;
    char*  ws  = (char*)d_ws;

    // workspace layout (bytes) — ~185.6 MB
    float* XP = (float*)(ws);                                   // 100663296
    float* X  = (float*)(ws + 100663296UL);                     // 33554432
    float* Y  = (float*)(ws + 134217728UL);                     // 33554432
    int*   m0 = (int*)(ws + 184549376UL);                       // 131072
    int*   m1 = (int*)(ws + 184680448UL);                       // 131072
    unsigned long long* exch_d = (unsigned long long*)(ws + 184811520UL); // 786432
    int*   cnt = (int*)(ws + 185597952UL);                      // 2048

    float* act_out = out + BB * HH;                             // 16384
    float* pol_out = act_out + BB * NDEPTH * LL;                // +131072

    hipMemsetAsync(cnt, 0, LL * sizeof(int), stream);

    maskcvt_kernel<<<dim3(NROWS / 256), dim3(256), 0, stream>>>(
        (const unsigned char*)mraw, m0);

    // embedding: X = x @ W_emb + b_emb, time-major rows (l*64+b)
    gemm_kernel<1, 1><<<dim3(2, 256), dim3(256), 0, stream>>>(
        x, W_emb, b_emb, X, NROWS, HH, nullptr, nullptr);

    float* Xc = X; float* Yc = Y;
    int* mc = m0; int* mn = m1;

    for (int d = 0; d < NDEPTH; ++d) {
        // compaction index at head of Yc (dead until scan overwrites it,
        // after its consumers gemm<3,0>/lnrows have run)
        int* rowidx = (int*)Yc;            // 32768 ints
        int* nactp  = ((int*)Yc) + NROWS;  // 64 ints

        mkidx_kernel<<<dim3(BB), dim3(512), 0, stream>>>(mc, rowidx, nactp);

        // xp = LN(Xrows @ W) for ACTIVE rows only, compacted per chain
        gemm_kernel<3, 0><<<dim3(6, 256), dim3(256), 0, stream>>>(
            Xc, W, nullptr, XP, NROWS, H3, rowidx, nactp);
        lnrows_kernel<<<dim3(NROWS), dim3(256), 0, stream>>>(
            XP, gammas, betas, bias3, nactp);

        // scan (blocks 0..191) + streaming action tiles (blocks 192..447)
        scanact_kernel<<<dim3(448), dim3(512), 0, stream>>>(
            XP, U, gammas + H3, betas + H3, mc, Yc, exch_d, d << 10,
            Xc, Wa1, ba1, Ua1, Wa2, ba2, mn, act_out, pol_out, d, cnt);

        { float* tmp = Xc; Xc = Yc; Yc = tmp; }
        { int* tmp = mc; mc = mn; mn = tmp; }
    }

    final_copy_kernel<<<dim3(BB), dim3(256), 0, stream>>>(Xc, out);
}

// Round 11
// 3287.374 us; speedup vs baseline: 2.5247x; 2.5247x over previous
//
#include <hip/hip_runtime.h>
#include <hip/hip_bf16.h>
#include <math.h>

// Problem constants (fixed by setup_inputs): B=64, L=512, D_IN=256, H=256, A=128, DEPTH=4
#define BB 64
#define LL 512
#define HH 256
#define H3 768
#define AA 128
#define NDEPTH 4
#define NROWS (LL*BB)   // 32768

// dedicated exchange region:
//   u64 exch[64 chains][2 parity][3 slices][256]  = 786,432 B
#define EXCH_U64_PER_CHAIN (2 * 3 * 256)

typedef float vf32x32 __attribute__((ext_vector_type(32)));

// ---------------------------------------------------------------------------
// Mask conversion: detect byte-bool vs int32/float32 layout on device.
// mask[0][1] is always true (lengths >= 256 > 1): byte layout -> raw[1]==1.
__global__ void maskcvt_kernel(const unsigned char* __restrict__ raw,
                               int* __restrict__ m)
{
    int i = blockIdx.x * blockDim.x + threadIdx.x;   // 32768 threads
    bool bytemode = (raw[1] == 1);
    int v;
    if (bytemode) v = raw[i] ? 1 : 0;
    else          v = (((const int*)raw)[i] != 0) ? 1 : 0;
    m[i] = v;
}

// ---------------------------------------------------------------------------
// Per-chain compaction index: rowidx[b*512+seq] = seq-th active l (ascending),
// nact[b] = count. Ballot prefix sum, one 512-thread block per chain.
__global__ __launch_bounds__(512) void mkidx_kernel(
    const int* __restrict__ m,      // [b*512+l]
    int* __restrict__ rowidx,       // [b*512+seq] -> l
    int* __restrict__ nact)         // [b]
{
    const int b    = blockIdx.x;
    const int tid  = threadIdx.x;   // = l
    const int lane = tid & 63;
    const int w    = tid >> 6;      // 8 waves
    __shared__ int wcnt[8];
    int pred = m[b * LL + tid];
    unsigned long long bal = __ballot(pred != 0);
    int below = __popcll(bal & ((1ull << lane) - 1ull));
    if (lane == 63) wcnt[w] = __popcll(bal);
    __syncthreads();
    int woff = 0;
#pragma unroll
    for (int i = 0; i < 8; ++i) woff += (i < w) ? wcnt[i] : 0;
    if (pred) rowidx[b * LL + woff + below] = tid;
    if (tid == 511) nact[b] = woff + wcnt[7];
}

// ---------------------------------------------------------------------------
// Tiled fp32 GEMM: C[M,N] = A[M,256] @ B[256,N]  (K fixed at 256)
// MODE 1: A[row,k] = A[(row&63)*131072 + (row>>6)*256 + k]   (x gather)
// MODE 3: compacted-chain gather: out row r=(b*512+seq) pulls A row
//         (rowidx[r]*64+b); whole 128-row tiles past nact[b] exit early.
// EPI 0: store acc; EPI 1: + bias[col]
template<int MODE, int EPI>
__global__ __launch_bounds__(256) void gemm_kernel(
    const float* __restrict__ A, const float* __restrict__ Bm,
    const float* __restrict__ bias,
    float* __restrict__ C, int M, int N,
    const int* __restrict__ ridx, const int* __restrict__ nact)
{
    __shared__ float As[16][136];
    __shared__ float Bs[16][136];
    const int tid = threadIdx.x;
    const int tx = tid & 15, ty = tid >> 4;
    const int row0 = blockIdx.y * 128, col0 = blockIdx.x * 128;

    int arow0 = 0, arow1 = 0;
    if (MODE == 3) {
        const int bb = row0 >> 9;               // chain of this tile
        const int na = nact[bb];
        if ((row0 & 511) >= na) return;         // fully-inactive tile: skip
        const int r0 = row0 + (tid >> 2);       // i=0 staging row
        const int r1 = r0 + 64;                 // i=1 staging row
        const int l0 = ((r0 & 511) < na) ? ridx[r0] : 0;
        const int l1 = ((r1 & 511) < na) ? ridx[r1] : 0;
        arow0 = l0 * 64 + bb;
        arow1 = l1 * 64 + bb;
    }

    float acc[8][8];
#pragma unroll
    for (int i = 0; i < 8; ++i)
#pragma unroll
        for (int j = 0; j < 8; ++j) acc[i][j] = 0.f;

    for (int kk = 0; kk < 256; kk += 16) {
#pragma unroll
        for (int i = 0; i < 2; ++i) {
            int aid = i * 256 + tid;
            int r   = aid >> 2;
            int k4  = (aid & 3) << 2;
            int rr  = row0 + r;
            float4 v;
            if (MODE == 1) {
                v = *(const float4*)(A + (rr & 63) * 131072 + (rr >> 6) * 256 + kk + k4);
            } else {
                int ar = i ? arow1 : arow0;
                v = *(const float4*)(A + ar * 256 + kk + k4);
            }
            As[k4 + 0][r] = v.x; As[k4 + 1][r] = v.y;
            As[k4 + 2][r] = v.z; As[k4 + 3][r] = v.w;

            int bid = i * 256 + tid;
            int bk  = bid >> 5;
            int c4  = (bid & 31) << 2;
            float4 w = *(const float4*)(Bm + (kk + bk) * N + col0 + c4);
            *(float4*)&Bs[bk][c4] = w;
        }
        __syncthreads();
#pragma unroll
        for (int k = 0; k < 16; ++k) {
            float a[8], bb2[8];
            *(float4*)&a[0]   = *(const float4*)&As[k][ty * 8];
            *(float4*)&a[4]   = *(const float4*)&As[k][ty * 8 + 4];
            *(float4*)&bb2[0] = *(const float4*)&Bs[k][tx * 8];
            *(float4*)&bb2[4] = *(const float4*)&Bs[k][tx * 8 + 4];
#pragma unroll
            for (int i = 0; i < 8; ++i)
#pragma unroll
                for (int j = 0; j < 8; ++j)
                    acc[i][j] += a[i] * bb2[j];
        }
        __syncthreads();
    }

#pragma unroll
    for (int i = 0; i < 8; ++i) {
        int row  = row0 + ty * 8 + i;
        int colb = col0 + tx * 8;
        float vout[8];
#pragma unroll
        for (int j = 0; j < 8; ++j) {
            float v = acc[i][j];
            if (EPI == 1) v += bias[colb + j];
            vout[j] = v;
        }
        *(float4*)&C[row * N + colb]     = *(float4*)&vout[0];
        *(float4*)&C[row * N + colb + 4] = *(float4*)&vout[4];
    }
}

// ---------------------------------------------------------------------------
// Row LayerNorm over 768 cols, in place, fused with gamma/beta and gate bias.
// Compacted-row variant: rows past nact[chain] are garbage -> skipped.
__global__ __launch_bounds__(256) void lnrows_kernel(
    float* __restrict__ XP, const float* __restrict__ g0,
    const float* __restrict__ b0, const float* __restrict__ gb,
    const int* __restrict__ nact)
{
    const int row = blockIdx.x;
    if ((row & 511) >= nact[row >> 9]) return;
    const int tid = threadIdx.x;
    float* p = XP + (long)row * H3;
    float v0 = p[tid], v1 = p[tid + 256], v2 = p[tid + 512];
    float s = v0 + v1 + v2;
    float q = v0 * v0 + v1 * v1 + v2 * v2;
#pragma unroll
    for (int off = 32; off >= 1; off >>= 1) {
        s += __shfl_xor(s, off);
        q += __shfl_xor(q, off);
    }
    __shared__ float rs4[4], rq4[4];
    if ((tid & 63) == 0) { rs4[tid >> 6] = s; rq4[tid >> 6] = q; }
    __syncthreads();
    float S = rs4[0] + rs4[1] + rs4[2] + rs4[3];
    float Q = rq4[0] + rq4[1] + rq4[2] + rq4[3];
    float mu  = S * (1.f / 768.f);
    float var = Q * (1.f / 768.f) - mu * mu;
    float r   = rsqrtf(var + 1e-5f);
    p[tid]       = g0[tid]       * (v0 - mu) * r + b0[tid]       + gb[tid];
    p[tid + 256] = g0[tid + 256] * (v1 - mu) * r + b0[tid + 256] + gb[tid + 256];
    p[tid + 512] = g0[tid + 512] * (v2 - mu) * r + b0[tid + 512] + gb[tid + 512];
}

// ---------------------------------------------------------------------------
// Combined dispatch: blocks [0,192) run the sequential GRU scan; blocks
// [192,448) compute XA = Xc@Wa1+ba1 as 128x128 tiles on the CUs the scan
// leaves idle. XA is independent of the scan (consumed only by gemmact
// afterwards); XA blocks RETIRE. [Round-10 lesson: do NOT put the heavier
// act path in here — its register footprint exceeds the scan's and forces
// the scan's U slice to spill (WRITE_SIZE 194 MB -> 1.08 GB, 2.1x slower).
// The XA path's footprint is below the scan's; VGPR 128, no spill.]
// Scan: 3 wgs/chain; thread (kg=tid>>5, cg=tid&31) owns k in [kg*16,+16) x
// cols {s*256+cg+32j} (bank=cg part[] writes: conflict-free, r6-verified).
// U via volatile loads -> AGPR/VGPR resident (VGPR 96-128; r7 proved forcing
// arch-VGPRs backfires). Packed (seq<<32|bits) u64 relaxed AGENT exchange,
// fused dual-poll, bounded s_sleep backoff. ~2.2us/active-step = LLC
// visibility floor (invariant across 5 sync variants, rounds 5-9).
__global__ __launch_bounds__(512, 2) void scan3_kernel(
    const float* __restrict__ XP,   // compacted (b*512+cs, 768), bias+LN folded
    const float* __restrict__ U,    // (256, 768)
    const float* __restrict__ g1, const float* __restrict__ b1,
    const int* __restrict__ mask,   // [b*512+l]
    float* __restrict__ Y,          // (L*B, 256)
    unsigned long long* __restrict__ exch,  // [64][2][3][256] u64 (dedicated)
    int seq0,                       // d<<10
    const float* __restrict__ Xc,   // (L*B, 256) current depth input
    const float* __restrict__ Wa1,  // (256, 128)
    const float* __restrict__ ba1,  // (128)
    float* __restrict__ XA)         // (L*B, 128) out
{
    __shared__ float h_cur[256];
    __shared__ float part[16][256];
    __shared__ float xp_lds[768];
    __shared__ float g1s[768], b1s[768];
    __shared__ int   mk[512];
    __shared__ float reds[4], redq[4];
    __shared__ float As[16][136];
    __shared__ float Bs[16][136];

    const int tid = threadIdx.x;

    if (blockIdx.x >= 192) {
        // ---- XA tile: 128 rows x 128 cols, K=256, 512 threads ----
        const int t    = blockIdx.x - 192;     // 0..255
        const int row0 = t * 128;
        const int tx   = tid & 15;             // 8 cols each
        const int ty4  = tid >> 4;             // 0..31, 4 rows each
        float xacc[4][8];
#pragma unroll
        for (int i = 0; i < 4; ++i)
#pragma unroll
            for (int j = 0; j < 8; ++j) xacc[i][j] = 0.f;

        for (int kk = 0; kk < 256; kk += 16) {
            {   // A stage: 128x16 (512 threads x float4 = one pass)
                int r  = tid >> 2;
                int k4 = (tid & 3) << 2;
                float4 v = *(const float4*)(Xc + (row0 + r) * 256 + kk + k4);
                As[k4 + 0][r] = v.x; As[k4 + 1][r] = v.y;
                As[k4 + 2][r] = v.z; As[k4 + 3][r] = v.w;
            }
            {   // B stage: 16x128 (512 threads x float4 = one pass)
                int bk = tid >> 5;
                int c4 = (tid & 31) << 2;
                float4 w = *(const float4*)(Wa1 + (kk + bk) * AA + c4);
                *(float4*)&Bs[bk][c4] = w;
            }
            __syncthreads();
#pragma unroll
            for (int k = 0; k < 16; ++k) {
                float a[4], bb2[8];
                *(float4*)&a[0]   = *(const float4*)&As[k][ty4 * 4];
                *(float4*)&bb2[0] = *(const float4*)&Bs[k][tx * 8];
                *(float4*)&bb2[4] = *(const float4*)&Bs[k][tx * 8 + 4];
#pragma unroll
                for (int i = 0; i < 4; ++i)
#pragma unroll
                    for (int j = 0; j < 8; ++j)
                        xacc[i][j] += a[i] * bb2[j];
            }
            __syncthreads();
        }
#pragma unroll
        for (int i = 0; i < 4; ++i) {
            int row  = row0 + ty4 * 4 + i;
            int colb = tx * 8;
            float vout[8];
#pragma unroll
            for (int j = 0; j < 8; ++j) vout[j] = xacc[i][j] + ba1[colb + j];
            *(float4*)&XA[row * AA + colb]     = *(float4*)&vout[0];
            *(float4*)&XA[row * AA + colb + 4] = *(float4*)&vout[4];
        }
        return;
    }

    // ---- scan path ----
    const int i0   = blockIdx.x;
    const int xcd  = i0 & 7;
    const int slot = i0 >> 3;              // 0..23
    const int b    = xcd + 8 * (slot / 3); // chain 0..63
    const int s    = slot % 3;             // slice 0..2
    const int kg   = tid >> 5;             // 16 k-groups (16 k each)
    const int cg   = tid & 31;             // col ownership: cg + 32*j
    const int q1   = (s + 1 >= 3) ? s - 2 : s + 1;
    const int q2   = (s + 2 >= 3) ? s - 1 : s + 2;

    // U slice -> registers via volatile loads (pinned against remat/sinking).
    vf32x32 u0v, u1v, u2v, u3v;
    {
        const volatile float* Uv = U;
        const int colbase = s * 256 + cg;
#pragma unroll
        for (int i = 0; i < 16; ++i) {
#pragma unroll
            for (int j = 0; j < 8; ++j) {
                const int f = i * 8 + j;
                float val = Uv[(kg * 16 + i) * H3 + colbase + 32 * j];
                if      (f < 32) u0v[f]      = val;
                else if (f < 64) u1v[f - 32] = val;
                else if (f < 96) u2v[f - 64] = val;
                else             u3v[f - 96] = val;
            }
        }
    }
    if (tid < 256) h_cur[tid] = 0.f;
    for (int i = tid; i < 768; i += 512) { g1s[i] = g1[i]; b1s[i] = b1[i]; }
    mk[tid] = mask[b * LL + tid];
    __syncthreads();

    unsigned long long* exb = exch + b * EXCH_U64_PER_CHAIN;
    int seq = seq0;

    for (int l = 0; l < LL; ++l) {
        if (!mk[l]) {
            // masked step: h unchanged, Y row = h (slice 0 writes)
            if (s == 0 && tid < 64) {
                float4 hv = *(const float4*)&h_cur[tid * 4];
                *(float4*)&Y[((long)l * BB + b) * HH + tid * 4] = hv;
            }
            continue;
        }
        seq++;
        const int par = seq & 1;
        const int cs  = seq - seq0 - 1;        // compacted XP row index

        // prefetch compacted xp row (in flight during GEMV)
        float4 xr4;
        if (tid < 192) xr4 = *(const float4*)(XP + ((long)(b * LL + cs)) * H3 + tid * 4);

        // slice GEMV: acc[j] = sum_{k in kg-chunk} U[k][colbase+32j] * h[k]
        float acc[8] = {0.f, 0.f, 0.f, 0.f, 0.f, 0.f, 0.f, 0.f};
#pragma unroll
        for (int i = 0; i < 4; ++i) {
            float4 hv = *(const float4*)&h_cur[kg * 16 + i * 4];   // broadcast
#pragma unroll
            for (int e = 0; e < 4; ++e) {
                const float hh = (e == 0) ? hv.x : (e == 1) ? hv.y
                               : (e == 2) ? hv.z : hv.w;
                const int ik = i * 4 + e;
#pragma unroll
                for (int j = 0; j < 8; ++j) {
                    const int f = ik * 8 + j;
                    const float uu = (f < 32) ? u0v[f]
                                   : (f < 64) ? u1v[f - 32]
                                   : (f < 96) ? u2v[f - 64]
                                   :            u3v[f - 96];
                    acc[j] += uu * hh;
                }
            }
        }
#pragma unroll
        for (int j = 0; j < 8; ++j)
            part[kg][cg + 32 * j] = acc[j];            // bank=cg: conflict-free
        __syncthreads();                               // B1: part complete

        if (tid < 192) *(float4*)&xp_lds[tid * 4] = xr4;

        float pre = 0.f, v0 = 0.f, v1 = 0.f, v2 = 0.f;
        if (tid < 256) {
            pre = part[0][tid];
#pragma unroll
            for (int gg = 1; gg < 16; ++gg) pre += part[gg][tid];

            // publish own slice value (data+seq packed, relaxed agent atomic)
            unsigned long long pk =
                ((unsigned long long)(unsigned)seq << 32) |
                (unsigned long long)__float_as_uint(pre);
            __hip_atomic_store(&exb[(par * 3 + s) * 256 + tid], pk,
                               __ATOMIC_RELAXED, __HIP_MEMORY_SCOPE_AGENT);

            // fused dual-poll: both peer loads in flight per retry; bounded
            // s_sleep keeps the spin preemption-friendly under profiling.
            unsigned long long x1 = 0, x2 = 0;
            bool d1 = false, d2 = false;
            int spins = 0;
            do {
                unsigned long long t1 =
                    __hip_atomic_load(&exb[(par * 3 + q1) * 256 + tid],
                                      __ATOMIC_RELAXED, __HIP_MEMORY_SCOPE_AGENT);
                unsigned long long t2 =
                    __hip_atomic_load(&exb[(par * 3 + q2) * 256 + tid],
                                      __ATOMIC_RELAXED, __HIP_MEMORY_SCOPE_AGENT);
                if (!d1 && (int)(t1 >> 32) == seq) { x1 = t1; d1 = true; }
                if (!d2 && (int)(t2 >> 32) == seq) { x2 = t2; d2 = true; }
                if (++spins > 8) __builtin_amdgcn_s_sleep(1);
            } while (!(d1 && d2));
            float w1 = __uint_as_float((unsigned)x1);
            float w2 = __uint_as_float((unsigned)x2);
            v0 = (s == 0) ? pre : ((q1 == 0) ? w1 : w2);
            v1 = (s == 1) ? pre : ((q1 == 1) ? w1 : w2);
            v2 = (s == 2) ? pre : ((q1 == 2) ? w1 : w2);

            float st = v0 + v1 + v2;
            float qt = v0 * v0 + v1 * v1 + v2 * v2;
#pragma unroll
            for (int off = 32; off >= 1; off >>= 1) {
                st += __shfl_xor(st, off);
                qt += __shfl_xor(qt, off);
            }
            if ((tid & 63) == 0) { reds[tid >> 6] = st; redq[tid >> 6] = qt; }
        }
        __syncthreads();                               // B2: stats partials

        if (tid < 256) {
            float S = reds[0] + reds[1] + reds[2] + reds[3];
            float Q = redq[0] + redq[1] + redq[2] + redq[3];
            float mu = S * (1.f / 768.f);
            float rs = rsqrtf(Q * (1.f / 768.f) - mu * mu + 1e-5f);
            float hp_r = g1s[tid]       * (v0 - mu) * rs + b1s[tid];
            float hp_z = g1s[256 + tid] * (v1 - mu) * rs + b1s[256 + tid];
            float hp_h = g1s[512 + tid] * (v2 - mu) * rs + b1s[512 + tid];
            float xr = xp_lds[tid], xz = xp_lds[256 + tid], xh = xp_lds[512 + tid];
            float r  = 1.f / (1.f + expf(-(xr + hp_r)));
            float z  = 1.f / (1.f + expf(-(xz + hp_z)));
            float hh = tanhf(xh + r * hp_h);
            float o  = z * h_cur[tid] + (1.f - z) * hh;   // active step: mt=1
            h_cur[tid] = o;
            if (s == 0) Y[((long)l * BB + b) * HH + tid] = o;
        }
        __syncthreads();                               // B3: h_cur ready
    }
}

// ---------------------------------------------------------------------------
// Fused T-GEMM + action head: per 128-row tile computes
// v = tanh(Hprev@Ua1 + XA) (Hprev = Y shifted by one l, zeros at l=0), then
// logits = v@Wa2 + ba2 reduced in-register (16-lane shuffle tree), softmax,
// decision, mask_out. T is never materialized.
__global__ __launch_bounds__(256) void gemmact_kernel(
    const float* __restrict__ Yprev,   // (L*B, 256)
    const float* __restrict__ Ua1,     // (256, 128)
    const float* __restrict__ XA,      // (L*B, 128): x@Wa1 + ba1
    const float* __restrict__ Wa2,     // (128, 2)
    const float* __restrict__ ba2,     // (2)
    const int* __restrict__ mask_in, int* __restrict__ mask_out,
    float* __restrict__ act_out, float* __restrict__ pol_out, int d)
{
    __shared__ float As[16][136];
    __shared__ float Bs[16][136];
    const int tid = threadIdx.x;
    const int tx = tid & 15, ty = tid >> 4;
    const int row0 = blockIdx.y * 128;

    float acc[8][8];
#pragma unroll
    for (int i = 0; i < 8; ++i)
#pragma unroll
        for (int j = 0; j < 8; ++j) acc[i][j] = 0.f;

    for (int kk = 0; kk < 256; kk += 16) {
#pragma unroll
        for (int i = 0; i < 2; ++i) {
            int aid = i * 256 + tid;
            int r   = aid >> 2;
            int k4  = (aid & 3) << 2;
            int rr  = row0 + r;
            float4 v;
            if (rr < 64) v = make_float4(0.f, 0.f, 0.f, 0.f);
            else         v = *(const float4*)(Yprev + (rr - 64) * 256 + kk + k4);
            As[k4 + 0][r] = v.x; As[k4 + 1][r] = v.y;
            As[k4 + 2][r] = v.z; As[k4 + 3][r] = v.w;

            int bid = i * 256 + tid;
            int bk  = bid >> 5;
            int c4  = (bid & 31) << 2;
            float4 w = *(const float4*)(Ua1 + (kk + bk) * AA + c4);
            *(float4*)&Bs[bk][c4] = w;
        }
        __syncthreads();
#pragma unroll
        for (int k = 0; k < 16; ++k) {
            float a[8], bb2[8];
            *(float4*)&a[0]   = *(const float4*)&As[k][ty * 8];
            *(float4*)&a[4]   = *(const float4*)&As[k][ty * 8 + 4];
            *(float4*)&bb2[0] = *(const float4*)&Bs[k][tx * 8];
            *(float4*)&bb2[4] = *(const float4*)&Bs[k][tx * 8 + 4];
#pragma unroll
            for (int i = 0; i < 8; ++i)
#pragma unroll
                for (int j = 0; j < 8; ++j)
                    acc[i][j] += a[i] * bb2[j];
        }
        __syncthreads();
    }

    // epilogue: tanh + per-row logit partials over this thread's 8 cols
    float p0[8], p1[8];
#pragma unroll
    for (int i = 0; i < 8; ++i) { p0[i] = 0.f; p1[i] = 0.f; }
#pragma unroll
    for (int i = 0; i < 8; ++i) {
        int row  = row0 + ty * 8 + i;
#pragma unroll
        for (int j = 0; j < 8; ++j) {
            int c   = tx * 8 + j;
            float v = tanhf(acc[i][j] + XA[row * AA + c]);
            p0[i] += v * Wa2[c * 2];
            p1[i] += v * Wa2[c * 2 + 1];
        }
    }
    // reduce across the 16 tx lanes (lane bits 0..3 -> stays in-wave)
#pragma unroll
    for (int off = 1; off < 16; off <<= 1) {
#pragma unroll
        for (int i = 0; i < 8; ++i) {
            p0[i] += __shfl_xor(p0[i], off);
            p1[i] += __shfl_xor(p1[i], off);
        }
    }
    if (tx == 0) {
#pragma unroll
        for (int i = 0; i < 8; ++i) {
            int row = row0 + ty * 8 + i;
            int l   = row >> 6, bb = row & 63;
            float l0 = p0[i] + ba2[0];
            float l1 = p1[i] + ba2[1];
            float m  = fmaxf(l0, l1);
            float e0 = expf(l0 - m), e1 = expf(l1 - m);
            float inv = 1.f / (e0 + e1);
            float q0 = e0 * inv, q1v = e1 * inv;
            int mt = mask_in[bb * LL + l];
            int a  = (q1v > q0) && mt;
            act_out[bb * (NDEPTH * LL) + d * LL + l] = a ? 1.f : 0.f;
            pol_out[bb * (NDEPTH * LL * 2) + d * (LL * 2) + l * 2 + 0] = q0;
            pol_out[bb * (NDEPTH * LL * 2) + d * (LL * 2) + l * 2 + 1] = q1v;
            mask_out[bb * LL + l] = a;
        }
    }
}

// ---------------------------------------------------------------------------
__global__ void final_copy_kernel(const float* __restrict__ X, float* __restrict__ out)
{
    int i = blockIdx.x * blockDim.x + threadIdx.x;   // 16384
    int bb = i >> 8, j = i & 255;
    out[i] = X[((long)(LL - 1) * BB + bb) * HH + j];
}

// ---------------------------------------------------------------------------
extern "C" void kernel_launch(void* const* d_in, const int* in_sizes, int n_in,
                              void* d_out, int out_size, void* d_ws, size_t ws_size,
                              hipStream_t stream)
{
    const float* x      = (const float*)d_in[0];
    const void*  mraw   = d_in[1];
    const float* W_emb  = (const float*)d_in[2];
    const float* b_emb  = (const float*)d_in[3];
    const float* W      = (const float*)d_in[4];
    const float* U      = (const float*)d_in[5];
    const float* bias3  = (const float*)d_in[6];
    const float* Wa1    = (const float*)d_in[7];
    const float* Ua1    = (const float*)d_in[8];
    const float* ba1    = (const float*)d_in[9];
    const float* Wa2    = (const float*)d_in[10];
    const float* ba2    = (const float*)d_in[11];
    const float* gammas = (const float*)d_in[12];
    const float* betas  = (const float*)d_in[13];

    float* out = (float*)d_out;
    char*  ws  = (char*)d_ws;

    // workspace layout (bytes) — 185.6 MB
    float* XP = (float*)(ws);                                   // 100663296
    float* X  = (float*)(ws + 100663296UL);                     // 33554432
    float* Y  = (float*)(ws + 134217728UL);                     // 33554432
    float* XA = (float*)(ws + 167772160UL);                     // 16777216
    int*   m0 = (int*)(ws + 184549376UL);                       // 131072
    int*   m1 = (int*)(ws + 184680448UL);                       // 131072
    unsigned long long* exch_d = (unsigned long long*)(ws + 184811520UL); // 786432

    float* act_out = out + BB * HH;                             // 16384
    float* pol_out = act_out + BB * NDEPTH * LL;                // +131072

    maskcvt_kernel<<<dim3(NROWS / 256), dim3(256), 0, stream>>>(
        (const unsigned char*)mraw, m0);

    // embedding: X = x @ W_emb + b_emb, time-major rows (l*64+b)
    gemm_kernel<1, 1><<<dim3(2, 256), dim3(256), 0, stream>>>(
        x, W_emb, b_emb, X, NROWS, HH, nullptr, nullptr);

    float* Xc = X; float* Yc = Y;
    int* mc = m0; int* mn = m1;

    for (int d = 0; d < NDEPTH; ++d) {
        // compaction index at head of Yc (dead until scan overwrites it,
        // after its consumers gemm<3,0>/lnrows have run)
        int* rowidx = (int*)Yc;            // 32768 ints
        int* nactp  = ((int*)Yc) + NROWS;  // 64 ints

        mkidx_kernel<<<dim3(BB), dim3(512), 0, stream>>>(mc, rowidx, nactp);

        // xp = LN(Xrows @ W) for ACTIVE rows only, compacted per chain
        gemm_kernel<3, 0><<<dim3(6, 256), dim3(256), 0, stream>>>(
            Xc, W, nullptr, XP, NROWS, H3, rowidx, nactp);
        lnrows_kernel<<<dim3(NROWS), dim3(256), 0, stream>>>(
            XP, gammas, betas, bias3, nactp);

        // scan (blocks 0..191) + concurrent XA GEMM (blocks 192..447)
        scan3_kernel<<<dim3(448), dim3(512), 0, stream>>>(
            XP, U, gammas + H3, betas + H3, mc, Yc, exch_d, d << 10,
            Xc, Wa1, ba1, XA);

        // fused T-GEMM + action head (T never materialized)
        gemmact_kernel<<<dim3(1, 256), dim3(256), 0, stream>>>(
            Yc, Ua1, XA, Wa2, ba2, mc, mn, act_out, pol_out, d);

        { float* tmp = Xc; Xc = Yc; Yc = tmp; }
        { int* tmp = mc; mc = mn; mn = tmp; }
    }

    final_copy_kernel<<<dim3(BB), dim3(256), 0, stream>>>(Xc, out);
}